// Round 8
// baseline (316.713 us; speedup 1.0000x reference)
//
#include <hip/hip_runtime.h>
#include <math.h>

#define BATCHN   8192
#define NMAT     4
#define PERS     24
#define NK       201
#define NPG      512     // path-groups of 16 paths
#define DSTR     124     // drift bounce row stride (halves)
#define HSTR     76      // hedge bounce row stride (halves)
#define GSC      (1.0f/4096.0f)   // exact pow2 pre-scale for f16 G fragments
#define GUNSC    4096.0f

typedef _Float16 f16;
typedef _Float16 f16x4 __attribute__((ext_vector_type(4)));
typedef _Float16 f16x8 __attribute__((ext_vector_type(8)));
typedef float    f32x4 __attribute__((ext_vector_type(4)));

template<int N> struct IC { static constexpr int v = N; };

// single-wave blocks: lgkmcnt(0) orders LDS write->read, no barrier needed
#define LDS_FENCE() asm volatile("s_waitcnt lgkmcnt(0)" ::: "memory")

__device__ __forceinline__ f16x8 relu8(f16x8 v){
#pragma unroll
  for (int i = 0; i < 8; ++i) v[i] = (v[i] > (f16)0.f) ? v[i] : (f16)0.f;
  return v;
}
__device__ __forceinline__ f16x8 cvt88(float4 a, float4 b){
  f16x8 r;
  r[0]=(f16)a.x; r[1]=(f16)a.y; r[2]=(f16)a.z; r[3]=(f16)a.w;
  r[4]=(f16)b.x; r[5]=(f16)b.y; r[6]=(f16)b.z; r[7]=(f16)b.w;
  return r;
}
__device__ __forceinline__ f16x4 cvt4(float4 a){
  f16x4 r; r[0]=(f16)a.x; r[1]=(f16)a.y; r[2]=(f16)a.z; r[3]=(f16)a.w; return r;
}

// ================= kernel 1: sequential drift scan (512 x 1 wave) =================
__global__ __launch_bounds__(64, 2)
void drift_scan(const float* __restrict__ nW0, const float* __restrict__ nb0,
                const float* __restrict__ nW1, const float* __restrict__ nb1,
                const float* __restrict__ nW2, const float* __restrict__ nb2,
                const float* __restrict__ nW3, const float* __restrict__ nb3,
                const float* __restrict__ rho, const float* __restrict__ V0,
                const float* __restrict__ noise1, const float* __restrict__ noise2,
                float* __restrict__ Sbuf, float* __restrict__ Cbuf,
                float* __restrict__ CstB, float* __restrict__ SfinB)
{
  __shared__ __align__(16) f16 bbD[16*DSTR];

  const int lane = threadIdx.x;
  const int L15  = lane & 15;
  const int G    = lane >> 4;
  const int gpath = blockIdx.x * 16 + L15;

  const float DTf = (float)(2.0/96.0);
  const float SDT = 0.14433756729740643f;
  const float DFf = (float)exp(-0.05 * 2.0 / 96.0);
  const float rho_s = rho[0];
  const float rt1m  = sqrtf(1.f - rho_s*rho_s);

  float S = 100.f, Vv = V0[0];

  auto maturity = [&](auto MC){
    constexpr int m = decltype(MC)::v;

    f16x8 aD1[6], aD2[6];  f16x4 bD1r[6], bD2r[6];  f32x4 w3r[6];
    f16x8 w0r[3][4];
#pragma unroll
    for (int t6 = 0; t6 < 6; ++t6){
      const int n  = t6 >> 1;
      const int o  = ((t6 & 1) << 4) + L15;
      const int ob = ((t6 & 1) << 4) + 4*G;
      const float* p1 = nW1 + (size_t)(((n*4+m)*32)+o)*32 + G*8;
      aD1[t6] = cvt88(*(const float4*)p1, *(const float4*)(p1+4));
      const float* p2 = nW2 + (size_t)(((n*4+m)*32)+o)*32 + G*8;
      aD2[t6] = cvt88(*(const float4*)p2, *(const float4*)(p2+4));
      bD1r[t6] = cvt4(*(const float4*)(nb1 + (n*4+m)*32 + ob));
      bD2r[t6] = cvt4(*(const float4*)(nb2 + (n*4+m)*32 + ob));
      w3r[t6]  = *(const f32x4*)(nW3 + (n*4+m)*32 + ob);
    }
    const float b30 = nb3[m], b31 = nb3[4+m], b32 = nb3[8+m];
#pragma unroll
    for (int n = 0; n < 3; ++n){
      f16x8 wt, ws, wvv, bz;
#pragma unroll
      for (int j = 0; j < 8; ++j){
        const int o = G*8 + j;
        const float* p = nW0 + (size_t)(((n*4+m)*32)+o)*3;
        wt[j]=(f16)p[0]; ws[j]=(f16)p[1]; wvv[j]=(f16)p[2];
        bz[j]=(f16)nb0[(n*4+m)*32+o];
      }
      w0r[n][0]=wt; w0r[n][1]=ws; w0r[n][2]=wvv; w0r[n][3]=bz;
    }
    float pn1 = noise1[(size_t)(m*PERS)*BATCHN + gpath];
    float pn2 = noise2[(size_t)(m*PERS)*BATCHN + gpath];
    float Cacc = 0.f;

#pragma unroll 1
    for (int s = 0; s < PERS; ++s){
      const int gstep = m*PERS + s;
      const float t = (float)gstep * DTf;
      float nn1 = 0.f, nn2 = 0.f;
      if (s+1 < PERS){
        nn1 = noise1[(size_t)(gstep+1)*BATCHN + gpath];
        nn2 = noise2[(size_t)(gstep+1)*BATCHN + gpath];
      }
      const f16 th=(f16)t, Sh=(f16)S, Vh=(f16)Vv;
      f16x8 bfr[3];
#pragma unroll
      for (int n = 0; n < 3; ++n)
        bfr[n] = relu8(w0r[n][0]*th + w0r[n][1]*Sh + w0r[n][2]*Vh + w0r[n][3]);
#pragma unroll
      for (int t6 = 0; t6 < 6; ++t6){
        f32x4 acc = {(float)bD1r[t6][0],(float)bD1r[t6][1],(float)bD1r[t6][2],(float)bD1r[t6][3]};
        acc = __builtin_amdgcn_mfma_f32_16x16x32_f16(aD1[t6], bfr[t6>>1], acc, 0,0,0);
        f16x4 o4;
        o4[0]=(f16)fmaxf(acc[0],0.f); o4[1]=(f16)fmaxf(acc[1],0.f);
        o4[2]=(f16)fmaxf(acc[2],0.f); o4[3]=(f16)fmaxf(acc[3],0.f);
        *(f16x4*)&bbD[L15*DSTR + t6*16 + 4*G] = o4;
      }
      LDS_FENCE();
      f16x8 bl[3];
#pragma unroll
      for (int n = 0; n < 3; ++n)
        bl[n] = *(const f16x8*)&bbD[L15*DSTR + n*32 + G*8];
      f32x4 c2[6];
#pragma unroll
      for (int t6 = 0; t6 < 6; ++t6){
        f32x4 acc = {(float)bD2r[t6][0],(float)bD2r[t6][1],(float)bD2r[t6][2],(float)bD2r[t6][3]};
        c2[t6] = __builtin_amdgcn_mfma_f32_16x16x32_f16(aD2[t6], bl[t6>>1], acc, 0,0,0);
      }
      float pr0=0.f, pr1=0.f, pr2=0.f;
#pragma unroll
      for (int t6 = 0; t6 < 6; ++t6){
        const f32x4 w4 = w3r[t6];
        const float pp = w4[0]*fmaxf(c2[t6][0],0.f)+w4[1]*fmaxf(c2[t6][1],0.f)
                       + w4[2]*fmaxf(c2[t6][2],0.f)+w4[3]*fmaxf(c2[t6][3],0.f);
        if (t6<2) pr0+=pp; else if (t6<4) pr1+=pp; else pr2+=pp;
      }
      pr0 += __shfl_xor(pr0,16); pr0 += __shfl_xor(pr0,32);
      pr1 += __shfl_xor(pr1,16); pr1 += __shfl_xor(pr1,32);
      pr2 += __shfl_xor(pr2,16); pr2 += __shfl_xor(pr2,32);
      const float r0=pr0+b30, r1=pr1+b31, r2=pr2+b32;
      const float sigS = r0/(1.f+fabsf(r0)*SDT);
      const float bV   = r1/(1.f+fabsf(r1)*SDT);
      const float sigV = r2/(1.f+fabsf(r2)*SDT);
      const float sr = S*0.05f;
      const float bS = sr/(1.f+fabsf(sr)*SDT);
      const float dW = SDT*pn2;
      const float dB = rho_s*dW + rt1m*SDT*pn1;
      const float c  = DFf*S*sigS*dW;
      Cacc += c;
      if (G == 0){   // stream pre-update S and c for the hedge phase
        Sbuf[(size_t)gpath*96 + gstep] = S;
        Cbuf[(size_t)gpath*96 + gstep] = c;
      }
      S  = S + bS*DTf + sigS*dB;
      Vv = fmaxf(Vv + bV*DTf + sigV*dW, 0.f);
      pn1 = nn1; pn2 = nn2;
    }
    if (G == 0){
      CstB [m*BATCHN + gpath] = Cacc;
      SfinB[m*BATCHN + gpath] = S;
    }
  };

  maturity(IC<0>{});
  maturity(IC<1>{});
  maturity(IC<2>{});
  maturity(IC<3>{});
}

// ============ kernel 2: batched hedge evaluation (4*512 x 1 wave, parallel) ============
__global__ __launch_bounds__(64, 2)
void hedge_batch(const float* __restrict__ hW0, const float* __restrict__ hb0,
                 const float* __restrict__ hW1, const float* __restrict__ hb1,
                 const float* __restrict__ hW2, const float* __restrict__ hb2,
                 const float* __restrict__ hW3, const float* __restrict__ hb3,
                 const float* __restrict__ Sbuf, const float* __restrict__ Cbuf,
                 float* __restrict__ Gbuf)
{
  __shared__ __align__(16) f16 bbH1[16*HSTR];
  __shared__ __align__(16) f16 bbH2[16*HSTR];

  const int m  = blockIdx.x >> 9;
  const int pg = blockIdx.x & 511;
  const int lane = threadIdx.x;
  const int L15  = lane & 15;
  const int G    = lane >> 4;
  const int gpath = pg*16 + L15;

  const float DTf = (float)(2.0/96.0);

  f16x8 aH[3][4][2];  f16x4 bHr[3][4];  f16x8 wh0r[2][3];
#pragma unroll
  for (int L = 0; L < 3; ++L){
    const float* W = (L==0)?hW1:(L==1)?hW2:hW3;
    const float* B = (L==0)?hb1:(L==1)?hb2:hb3;
#pragma unroll
    for (int mt = 0; mt < 4; ++mt){
#pragma unroll
      for (int kt = 0; kt < 2; ++kt){
        const float* src = W + (size_t)m*4096 + (16*mt + L15)*64 + kt*32 + G*8;
        aH[L][mt][kt] = cvt88(*(const float4*)src, *(const float4*)(src+4));
      }
      bHr[L][mt] = cvt4(*(const float4*)(B + m*64 + mt*16 + 4*G));
    }
  }
#pragma unroll
  for (int kt = 0; kt < 2; ++kt){
    f16x8 wt, ws, bz;
#pragma unroll
    for (int j = 0; j < 8; ++j){
      const int o = kt*32 + G*8 + j;
      wt[j]=(f16)hW0[m*128 + o*2];
      ws[j]=(f16)hW0[m*128 + o*2 + 1];
      bz[j]=(f16)hb0[m*64 + o];
    }
    wh0r[kt][0]=wt; wh0r[kt][1]=ws; wh0r[kt][2]=bz;
  }

  float Gacc[16];
#pragma unroll
  for (int j = 0; j < 16; ++j) Gacc[j] = 0.f;

  float pS = Sbuf[(size_t)gpath*96 + m*PERS];
  float pc = Cbuf[(size_t)gpath*96 + m*PERS];

#pragma unroll 1
  for (int s = 0; s < PERS; ++s){
    const float t  = (float)(m*PERS + s) * DTf;
    const float Sj = pS;
    const float c  = pc;
    if (s+1 < PERS){
      pS = Sbuf[(size_t)gpath*96 + m*PERS + s + 1];
      pc = Cbuf[(size_t)gpath*96 + m*PERS + s + 1];
    }
    const f16 th=(f16)t, Sh=(f16)Sj;
    f16x8 bh0 = relu8(wh0r[0][0]*th + wh0r[0][1]*Sh + wh0r[0][2]);
    f16x8 bh1 = relu8(wh0r[1][0]*th + wh0r[1][1]*Sh + wh0r[1][2]);
#pragma unroll
    for (int mt = 0; mt < 4; ++mt){
      f32x4 acc = {(float)bHr[0][mt][0],(float)bHr[0][mt][1],(float)bHr[0][mt][2],(float)bHr[0][mt][3]};
      acc = __builtin_amdgcn_mfma_f32_16x16x32_f16(aH[0][mt][0], bh0, acc, 0,0,0);
      acc = __builtin_amdgcn_mfma_f32_16x16x32_f16(aH[0][mt][1], bh1, acc, 0,0,0);
      f16x4 o4;
      o4[0]=(f16)fmaxf(acc[0],0.f); o4[1]=(f16)fmaxf(acc[1],0.f);
      o4[2]=(f16)fmaxf(acc[2],0.f); o4[3]=(f16)fmaxf(acc[3],0.f);
      *(f16x4*)&bbH1[L15*HSTR + mt*16 + 4*G] = o4;
    }
    LDS_FENCE();
    f16x8 x0 = *(const f16x8*)&bbH1[L15*HSTR +      G*8];
    f16x8 x1 = *(const f16x8*)&bbH1[L15*HSTR + 32 + G*8];
#pragma unroll
    for (int mt = 0; mt < 4; ++mt){
      f32x4 acc = {(float)bHr[1][mt][0],(float)bHr[1][mt][1],(float)bHr[1][mt][2],(float)bHr[1][mt][3]};
      acc = __builtin_amdgcn_mfma_f32_16x16x32_f16(aH[1][mt][0], x0, acc, 0,0,0);
      acc = __builtin_amdgcn_mfma_f32_16x16x32_f16(aH[1][mt][1], x1, acc, 0,0,0);
      f16x4 o4;
      o4[0]=(f16)fmaxf(acc[0],0.f); o4[1]=(f16)fmaxf(acc[1],0.f);
      o4[2]=(f16)fmaxf(acc[2],0.f); o4[3]=(f16)fmaxf(acc[3],0.f);
      *(f16x4*)&bbH2[L15*HSTR + mt*16 + 4*G] = o4;
    }
    LDS_FENCE();
    x0 = *(const f16x8*)&bbH2[L15*HSTR +      G*8];
    x1 = *(const f16x8*)&bbH2[L15*HSTR + 32 + G*8];
#pragma unroll
    for (int mt = 0; mt < 4; ++mt){
      f32x4 acc = {(float)bHr[2][mt][0],(float)bHr[2][mt][1],(float)bHr[2][mt][2],(float)bHr[2][mt][3]};
      acc = __builtin_amdgcn_mfma_f32_16x16x32_f16(aH[2][mt][0], x0, acc, 0,0,0);
      acc = __builtin_amdgcn_mfma_f32_16x16x32_f16(aH[2][mt][1], x1, acc, 0,0,0);
      Gacc[mt*4+0] += c*fmaxf(acc[0],0.f);
      Gacc[mt*4+1] += c*fmaxf(acc[1],0.f);
      Gacc[mt*4+2] += c*fmaxf(acc[2],0.f);
      Gacc[mt*4+3] += c*fmaxf(acc[3],0.f);
    }
  }

  // store G row-major [m][pg][row 0..63][path 0..15]
#pragma unroll
  for (int mt = 0; mt < 4; ++mt)
#pragma unroll
    for (int jj = 0; jj < 4; ++jj)
      Gbuf[((size_t)(m*NPG + pg)*64 + mt*16 + 4*G + jj)*16 + L15] = Gacc[mt*4+jj];
}

// ============ kernel 3: payoff epilogue (4*512 x 1 wave) ============
__global__ __launch_bounds__(64, 2)
void payoff_kernel(const float* __restrict__ hW4, const float* __restrict__ hb4,
                   const float* __restrict__ strikes,
                   const float* __restrict__ CstB, const float* __restrict__ SfinB,
                   const float* __restrict__ Gbuf,
                   float* __restrict__ part1, float* __restrict__ part2)
{
  const int m  = blockIdx.x >> 9;
  const int pg = blockIdx.x & 511;
  const int lane = threadIdx.x;
  const int L15  = lane & 15;
  const int G    = lane >> 4;
  const int gpath = pg*16 + L15;

  const float discm = (float)exp(-0.05*(2.0/96.0)*(double)(PERS*(m+1)));
  const float Sfin  = SfinB[m*BATCHN + gpath];

  float Cc[4];
  f16x8 Bf[4][2];
#pragma unroll
  for (int q = 0; q < 4; ++q){
    Cc[q] = 0.f;
    if (q <= m){
      Cc[q] = CstB[q*BATCHN + gpath];
#pragma unroll
      for (int kt = 0; kt < 2; ++kt){
        f16x8 b;
#pragma unroll
        for (int j = 0; j < 8; ++j){
          const float g = Gbuf[((size_t)(q*NPG + pg)*64 + kt*32 + G*8 + j)*16 + L15];
          b[j] = (f16)(g * GSC);
        }
        Bf[q][kt] = b;
      }
    } else {
      f16x8 z = {};
      Bf[q][0] = z; Bf[q][1] = z;
    }
  }

#pragma unroll 1
  for (int mt = 0; mt < 13; ++mt){
    const int ksr = min(16*mt + L15, 200);
    f32x4 acc = {0.f, 0.f, 0.f, 0.f};
#pragma unroll
    for (int q = 0; q < 4; ++q){
      if (q <= m){
#pragma unroll
        for (int kt = 0; kt < 2; ++kt){
          const float* ap = hW4 + (size_t)(q*804 + ksr*4 + m)*64 + kt*32 + G*8;
          const f16x8 a = cvt88(*(const float4*)ap, *(const float4*)(ap+4));
          acc = __builtin_amdgcn_mfma_f32_16x16x32_f16(a, Bf[q][kt], acc, 0,0,0);
        }
      }
    }
#pragma unroll
    for (int r = 0; r < 4; ++r){
      const int k2  = 16*mt + 4*G + r;
      const int k2c = min(k2, 200);
      float ac = acc[r] * GUNSC;
#pragma unroll
      for (int q = 0; q < 4; ++q)
        if (q <= m) ac = fmaf(hb4[q*804 + k2c*4 + m], Cc[q], ac);
      const float pay = discm*fmaxf(Sfin - strikes[k2c], 0.f) - ac;
      float s1 = pay, s2 = pay*pay;
      s1 += __shfl_xor(s1,1); s1 += __shfl_xor(s1,2);
      s1 += __shfl_xor(s1,4); s1 += __shfl_xor(s1,8);
      s2 += __shfl_xor(s2,1); s2 += __shfl_xor(s2,2);
      s2 += __shfl_xor(s2,4); s2 += __shfl_xor(s2,8);
      if (L15 == 0 && k2 < NK){
        part1[(size_t)(m*NK + k2)*NPG + pg] = s1;
        part2[(size_t)(m*NK + k2)*NPG + pg] = s2;
      }
    }
  }
}

// ============ kernel 4: finalize ============
__global__ __launch_bounds__(256)
void finalize_kernel(const float* __restrict__ part1,
                     const float* __restrict__ part2,
                     float* __restrict__ out)
{
  const int j   = blockIdx.x;          // j = m*NK + k
  const int m   = j / NK, k = j % NK;
  const int tid = threadIdx.x;
  double s1 = (double)part1[(size_t)j*NPG + tid]
            + (double)part1[(size_t)j*NPG + 256 + tid];
  double s2 = (double)part2[(size_t)j*NPG + tid]
            + (double)part2[(size_t)j*NPG + 256 + tid];
#pragma unroll
  for (int d = 32; d > 0; d >>= 1){
    s1 += __shfl_down(s1, d, 64);
    s2 += __shfl_down(s2, d, 64);
  }
  __shared__ double r1[4], r2[4];
  if ((tid & 63) == 0){ r1[tid>>6] = s1; r2[tid>>6] = s2; }
  __syncthreads();
  if (tid == 0){
    const double t1 = r1[0]+r1[1]+r1[2]+r1[3];
    const double t2 = r2[0]+r2[1]+r2[2]+r2[3];
    const double mean = t1 / 8192.0;
    const double var  = (t2 - t1*t1/8192.0) / 8191.0;   // ddof=1
    out[k*NMAT + m]            = (float)mean;
    out[NK*NMAT + k*NMAT + m]  = (float)var;
  }
}

extern "C" void kernel_launch(void* const* d_in, const int* in_sizes, int n_in,
                              void* d_out, int out_size, void* d_ws, size_t ws_size,
                              hipStream_t stream)
{
  (void)in_sizes; (void)n_in; (void)out_size; (void)ws_size;
  const float* nW0 = (const float*)d_in[0];
  const float* nb0 = (const float*)d_in[1];
  const float* nW1 = (const float*)d_in[2];
  const float* nb1 = (const float*)d_in[3];
  const float* nW2 = (const float*)d_in[4];
  const float* nb2 = (const float*)d_in[5];
  const float* nW3 = (const float*)d_in[6];
  const float* nb3 = (const float*)d_in[7];
  const float* hW0 = (const float*)d_in[8];
  const float* hb0 = (const float*)d_in[9];
  const float* hW1 = (const float*)d_in[10];
  const float* hb1 = (const float*)d_in[11];
  const float* hW2 = (const float*)d_in[12];
  const float* hb2 = (const float*)d_in[13];
  const float* hW3 = (const float*)d_in[14];
  const float* hb3 = (const float*)d_in[15];
  const float* hW4 = (const float*)d_in[16];
  const float* hb4 = (const float*)d_in[17];
  const float* rho = (const float*)d_in[18];
  const float* V0  = (const float*)d_in[19];
  const float* strikes = (const float*)d_in[20];
  const float* noise1  = (const float*)d_in[21];
  const float* noise2  = (const float*)d_in[22];

  float* Sbuf  = (float*)d_ws;                 // [8192][96]
  float* Cbuf  = Sbuf  + (size_t)BATCHN*96;    // [8192][96]
  float* CstB  = Cbuf  + (size_t)BATCHN*96;    // [4][8192]
  float* SfinB = CstB  + (size_t)NMAT*BATCHN;  // [4][8192]
  float* Gbuf  = SfinB + (size_t)NMAT*BATCHN;  // [4][512][64][16]
  float* part1 = Gbuf  + (size_t)NMAT*NPG*64*16;
  float* part2 = part1 + (size_t)NMAT*NK*NPG;

  drift_scan<<<NPG, 64, 0, stream>>>(nW0, nb0, nW1, nb1, nW2, nb2, nW3, nb3,
                                     rho, V0, noise1, noise2,
                                     Sbuf, Cbuf, CstB, SfinB);

  hedge_batch<<<NMAT*NPG, 64, 0, stream>>>(hW0, hb0, hW1, hb1, hW2, hb2, hW3, hb3,
                                           Sbuf, Cbuf, Gbuf);

  payoff_kernel<<<NMAT*NPG, 64, 0, stream>>>(hW4, hb4, strikes, CstB, SfinB, Gbuf,
                                             part1, part2);

  finalize_kernel<<<NMAT*NK, 256, 0, stream>>>(part1, part2, (float*)d_out);
}